// Round 14
// baseline (250.461 us; speedup 1.0000x reference)
//
#include <hip/hip_runtime.h>
#include <hip/hip_fp16.h>

#define NV 50000
#define NVP 50176
#define BDIM 64
#define DIN 1024
#define KFAN 32
#define DOUT 256
#define KSTEPS (DIN / 32)
#define XPK_N (KSTEPS * 512)   // uint4 elements per xpk copy (256 KB)
#define OPC_CHUNK 128
#define OPC_NCH (NVP / OPC_CHUNK)  // 392

typedef short bf16x8 __attribute__((ext_vector_type(8)));
typedef _Float16 f16x8 __attribute__((ext_vector_type(8)));
typedef float f32x4 __attribute__((ext_vector_type(4)));

__device__ __forceinline__ unsigned short bf16_rtn(float f) {
  unsigned u = __float_as_uint(f);
  return (unsigned short)((u + 0x7fffu + ((u >> 16) & 1u)) >> 16);
}
__device__ __forceinline__ float bf16_to_f(unsigned short v) {
  return __uint_as_float(((unsigned)v) << 16);
}
__device__ __forceinline__ unsigned short f16_rn(float f) {
  return __half_as_ushort(__float2half(f));
}

// W0 (fp32, row-major) -> Wpk (f16, fragment-sequential order).
// Reads are PURE SEQUENTIAL STREAM: thread t reads 8 consecutive floats
// (2x float4, wave = 2KB contiguous). This kernel doubles as the decisive
// streaming-read-bandwidth probe for this box.
// Dest layout: uint4 index (nblk*32 + ks)*64 + rq*16 + rr holds
// W0[nblk*16 + rr][ks*32 + rq*8 .. +7] as 8 f16.
__global__ __launch_bounds__(256) void repack_w(const float* __restrict__ W0,
                                                uint4* __restrict__ Wpk) {
  const size_t F = ((size_t)blockIdx.x * 256 + threadIdx.x) * 8;  // float idx
  float4 a = *(const float4*)(W0 + F);
  float4 b = *(const float4*)(W0 + F + 4);
  const int row = (int)(F >> 10);
  const int col8 = ((int)F >> 3) & 127;   // ks*4 + rq
  const int ks = col8 >> 2;
  const int rq = col8 & 3;
  const int nblk = row >> 4;
  const int rr = row & 15;
  uint4 o;
  o.x = f16_rn(a.x) | ((unsigned)f16_rn(a.y) << 16);
  o.y = f16_rn(a.z) | ((unsigned)f16_rn(a.w) << 16);
  o.z = f16_rn(b.x) | ((unsigned)f16_rn(b.y) << 16);
  o.w = f16_rn(b.z) | ((unsigned)f16_rn(b.w) << 16);
  Wpk[(size_t)(nblk * 32 + ks) * 64 + rq * 16 + rr] = o;
}

// Pack x[64][1024] into MFMA B-fragment lane order as f16 hi + f16 lo,
// replicated 8x so each XCD's L2 can hold a private copy.
__global__ __launch_bounds__(256) void pack_x(const float* __restrict__ x,
                                              uint4* __restrict__ xpk8) {
  int tid = blockIdx.x * 256 + threadIdx.x;  // 0..8191
  int ks = tid >> 8;
  int g = (tid >> 6) & 3;
  int l = tid & 63;
  int b = g * 16 + (l & 15);
  int k0 = ks * 32 + (l >> 4) * 8;
  unsigned hi[8], lo[8];
#pragma unroll
  for (int j = 0; j < 8; ++j) {
    float f = x[b * DIN + k0 + j];
    unsigned short h = f16_rn(f);
    hi[j] = h;
    float fh = __half2float(__ushort_as_half(h));
    lo[j] = f16_rn(f - fh);
  }
  uint4 vh, vl;
  vh.x = hi[0] | (hi[1] << 16); vh.y = hi[2] | (hi[3] << 16);
  vh.z = hi[4] | (hi[5] << 16); vh.w = hi[6] | (hi[7] << 16);
  vl.x = lo[0] | (lo[1] << 16); vl.y = lo[2] | (lo[3] << 16);
  vl.z = lo[4] | (lo[5] << 16); vl.w = lo[6] | (lo[7] << 16);
  int idx = (ks * 4 + g) * 128 + l;
#pragma unroll
  for (int c = 0; c < 8; ++c) {
    xpk8[(size_t)c * XPK_N + idx] = vh;
    xpk8[(size_t)c * XPK_N + idx + 64] = vl;
  }
}

// h[n][b] = relu(sum_d W0[n][d]*x[b][d] + b0[n]) via f16 MFMA (W single-f16,
// x split hi/lo). W read from Wpk PURELY SEQUENTIALLY: 1KB contiguous per
// wave instruction, block walks its 32KB linearly. Register pipeline:
// W 4 deep, x 2 deep, fully unrolled, no LDS, no barriers.
__global__ __launch_bounds__(64) void layer0_mfma(
    const uint4* __restrict__ Wpk, const float* __restrict__ b0,
    const uint4* __restrict__ xpk8, unsigned short* __restrict__ h)
{
  const int lane = threadIdx.x;
  const int nblk = blockIdx.x;
  const int n_base = nblk * 16;  // NV = 3125*16 exactly
  const int rq = lane >> 4;
  const int rr = lane & 15;
  const uint4* wp = Wpk + (size_t)nblk * 32 * 64 + lane;
  const uint4* xsrc = xpk8 + (size_t)(nblk & 7) * XPK_N;

  f32x4 acc[4];
#pragma unroll
  for (int g = 0; g < 4; ++g) acc[g] = (f32x4){0.f, 0.f, 0.f, 0.f};

  uint4 wpre[4];       // 4-deep W pipeline (sequential stream)
  uint4 xpre[2][8];    // 2-deep x pipeline (L2-resident source)

#pragma unroll
  for (int d = 0; d < 4; ++d) wpre[d] = wp[d * 64];
#pragma unroll
  for (int d = 0; d < 2; ++d)
#pragma unroll
    for (int g = 0; g < 4; ++g) {
      xpre[d][g * 2]     = xsrc[d * 512 + g * 128 + lane];
      xpre[d][g * 2 + 1] = xsrc[d * 512 + g * 128 + 64 + lane];
    }

#pragma unroll
  for (int ks = 0; ks < KSTEPS; ++ks) {
    const int sw = ks & 3;
    const int sx = ks & 1;
    uint4 wv = wpre[sw];
    if (ks + 4 < KSTEPS) wpre[sw] = wp[(ks + 4) * 64];
    f16x8 wf = __builtin_bit_cast(f16x8, wv);
#pragma unroll
    for (int g = 0; g < 4; ++g) {
      f16x8 xh = __builtin_bit_cast(f16x8, xpre[sx][g * 2]);
      f16x8 xl = __builtin_bit_cast(f16x8, xpre[sx][g * 2 + 1]);
      acc[g] = __builtin_amdgcn_mfma_f32_16x16x32_f16(wf, xh, acc[g], 0, 0, 0);
      acc[g] = __builtin_amdgcn_mfma_f32_16x16x32_f16(wf, xl, acc[g], 0, 0, 0);
    }
    if (ks + 2 < KSTEPS) {
      const int xb = (ks + 2) * 512;
#pragma unroll
      for (int g = 0; g < 4; ++g) {
        xpre[sx][g * 2]     = xsrc[xb + g * 128 + lane];
        xpre[sx][g * 2 + 1] = xsrc[xb + g * 128 + 64 + lane];
      }
    }
  }

  // C layout: col = rr (b sub), row = rq*4 + r (n sub)
#pragma unroll
  for (int r = 0; r < 4; ++r) {
    int n = n_base + rq * 4 + r;
    float bias = b0[n];
#pragma unroll
    for (int g = 0; g < 4; ++g) {
      float v = fmaxf(acc[g][r] + bias, 0.f);
      h[(size_t)n * BDIM + g * 16 + rr] = bf16_rtn(v);
    }
  }
}

// h_new[n][b] = relu(sum_k wv[n][k] * h[src[n][k]][b]); one wave per n.
__global__ __launch_bounds__(256) void sparse_layer(
    const unsigned short* __restrict__ hin, const float* __restrict__ wv,
    const int* __restrict__ src, unsigned short* __restrict__ hout)
{
  const int lane = threadIdx.x & 63;
  int n = blockIdx.x * 4 + (threadIdx.x >> 6);
  n = __builtin_amdgcn_readfirstlane(n);
  const float* wrow = wv + (size_t)n * KFAN;
  const int* srow = src + (size_t)n * KFAN;
  float acc = 0.f;
#pragma unroll
  for (int k = 0; k < KFAN; ++k) {
    int s = srow[k];      // uniform scalar load
    float w = wrow[k];    // uniform scalar load
    acc = fmaf(w, bf16_to_f(hin[(size_t)s * BDIM + lane]), acc);
  }
  hout[(size_t)n * BDIM + lane] = bf16_rtn(fmaxf(acc, 0.f));
}

// hT[b][n] = h[n][b]; coalesced reads, 16B/lane stores; zero-fills n-pad.
__global__ __launch_bounds__(256) void transpose_h(
    const unsigned short* __restrict__ h, unsigned short* __restrict__ hT)
{
  const int lane = threadIdx.x & 63;              // b
  const int wv = threadIdx.x >> 6;                // wave in block
  const int n0 = (blockIdx.x * 4 + wv) * 8;       // 8 n per wave
  unsigned short v[8];
#pragma unroll
  for (int i = 0; i < 8; ++i) {
    int n = n0 + i;
    v[i] = (n < NV) ? h[(size_t)n * BDIM + lane] : (unsigned short)0;
  }
  uint4 o;
  o.x = v[0] | ((unsigned)v[1] << 16);
  o.y = v[2] | ((unsigned)v[3] << 16);
  o.z = v[4] | ((unsigned)v[5] << 16);
  o.w = v[6] | ((unsigned)v[7] << 16);
  *(uint4*)(hT + (size_t)lane * NVP + n0) = o;
}

// part[dtile][chunk][d_local][b] over 128-n chunks, split-bf16 MFMA.
__global__ __launch_bounds__(64) void out_partial_mfma(
    const unsigned short* __restrict__ hT, const float* __restrict__ Wout,
    float* __restrict__ part)
{
  const int lane = threadIdx.x;
  const int rq = lane >> 4;
  const int rr = lane & 15;
  const int dtile = blockIdx.x;   // 0..3
  const int chunk = blockIdx.y;   // 0..391

  f32x4 acc[4][4];
#pragma unroll
  for (int f = 0; f < 4; ++f)
#pragma unroll
    for (int g = 0; g < 4; ++g) acc[f][g] = (f32x4){0.f, 0.f, 0.f, 0.f};

#pragma unroll
  for (int ks = 0; ks < OPC_CHUNK / 32; ++ks) {
    const int n0 = chunk * OPC_CHUNK + ks * 32 + rq * 8;
    bf16x8 hb[4];
#pragma unroll
    for (int g = 0; g < 4; ++g)
      hb[g] = *(const bf16x8*)(hT + (size_t)(g * 16 + rr) * NVP + n0);
    int nb = n0 > (NV - 8) ? (NV - 8) : n0;  // pad region: hb==0 -> contributes 0
#pragma unroll
    for (int f = 0; f < 4; ++f) {
      const float* wp = Wout + (size_t)(dtile * 64 + f * 16 + rr) * NV + nb;
      float4 a0 = *(const float4*)(wp);
      float4 a1 = *(const float4*)(wp + 4);
      float wf[8] = {a0.x, a0.y, a0.z, a0.w, a1.x, a1.y, a1.z, a1.w};
      bf16x8 whi, wlo;
#pragma unroll
      for (int e = 0; e < 8; ++e) {
        unsigned u = __float_as_uint(wf[e]);
        whi[e] = (short)(u >> 16);
        float l = wf[e] - __uint_as_float(u & 0xffff0000u);
        wlo[e] = (short)bf16_rtn(l);
      }
#pragma unroll
      for (int g = 0; g < 4; ++g) {
        acc[f][g] = __builtin_amdgcn_mfma_f32_16x16x32_bf16(whi, hb[g], acc[f][g], 0, 0, 0);
        acc[f][g] = __builtin_amdgcn_mfma_f32_16x16x32_bf16(wlo, hb[g], acc[f][g], 0, 0, 0);
      }
    }
  }
  float* pbase = part + ((size_t)dtile * OPC_NCH + chunk) * 4096;
#pragma unroll
  for (int f = 0; f < 4; ++f)
#pragma unroll
    for (int g = 0; g < 4; ++g)
#pragma unroll
      for (int r = 0; r < 4; ++r)
        pbase[(f * 16 + rq * 4 + r) * 64 + g * 16 + rr] = acc[f][g][r];
}

__global__ __launch_bounds__(256) void out_reduce(
    const float* __restrict__ part, const float* __restrict__ bout,
    float* __restrict__ out)
{
  int tid = blockIdx.x * 256 + threadIdx.x;  // 16384 threads
  int b = tid & 63;
  int d = tid >> 6;
  int dtile = d >> 6;
  int dd = d & 63;
  float s = bout[d];
  for (int c = 0; c < OPC_NCH; ++c)
    s += part[((size_t)dtile * OPC_NCH + c) * 4096 + dd * 64 + b];
  out[(size_t)b * DOUT + d] = s;
}

extern "C" void kernel_launch(void* const* d_in, const int* in_sizes, int n_in,
                              void* d_out, int out_size, void* d_ws, size_t ws_size,
                              hipStream_t stream)
{
  const float* x    = (const float*)d_in[0];
  const float* W0   = (const float*)d_in[1];
  const float* b0   = (const float*)d_in[2];
  const float* Wv   = (const float*)d_in[3];
  const float* Wout = (const float*)d_in[4];
  const float* bout = (const float*)d_in[5];
  const int*   src  = (const int*)d_in[6];
  float* out = (float*)d_out;

  char* ws = (char*)d_ws;
  const size_t hbf = (size_t)NV * BDIM * 2;       // 6.4 MB
  const size_t hTb = (size_t)NVP * BDIM * 2;      // 6.42 MB
  const size_t xpkb = (size_t)8 * XPK_N * 16;     // 2 MB
  const size_t partb = (size_t)4 * OPC_NCH * 4096 * 4;  // 25.7 MB
  unsigned short* hb0 = (unsigned short*)ws;
  unsigned short* hb1 = (unsigned short*)(ws + hbf);
  unsigned short* hT  = (unsigned short*)(ws + 2 * hbf);
  uint4* xpk8 = (uint4*)(ws + 2 * hbf + hTb);
  float* part = (float*)(ws + 2 * hbf + hTb + xpkb);
  uint4* Wpk  = (uint4*)(ws + 2 * hbf + hTb + xpkb + partb);  // 102.4 MB

  pack_x<<<32, 256, 0, stream>>>(x, xpk8);
  repack_w<<<(NV * DIN / 8) / 256, 256, 0, stream>>>(W0, Wpk);
  layer0_mfma<<<NV / 16, 64, 0, stream>>>(Wpk, b0, xpk8, hb0);

  const size_t lstride = (size_t)NV * KFAN;
  sparse_layer<<<NV / 4, 256, 0, stream>>>(hb0, Wv, src, hb1);
  sparse_layer<<<NV / 4, 256, 0, stream>>>(hb1, Wv + lstride, src + lstride, hb0);
  sparse_layer<<<NV / 4, 256, 0, stream>>>(hb0, Wv + 2 * lstride, src + 2 * lstride, hb1);

  transpose_h<<<NVP / 32, 256, 0, stream>>>(hb1, hT);
  out_partial_mfma<<<dim3(4, OPC_NCH), 64, 0, stream>>>(hT, Wout, part);
  out_reduce<<<(BDIM * DOUT) / 256, 256, 0, stream>>>(part, bout, out);
}

// Round 15
// 183.736 us; speedup vs baseline: 1.3632x; 1.3632x over previous
//
#include <hip/hip_runtime.h>

#define NV 50000
#define NVP 50176
#define BDIM 64
#define DIN 1024
#define KFAN 32
#define DOUT 256
#define KSTEPS (DIN / 32)
#define XPK_N (KSTEPS * 512)   // uint4 elements per xpk copy (256 KB)
#define OPC_CHUNK 128
#define OPC_NCH (NVP / OPC_CHUNK)  // 392

typedef short bf16x8 __attribute__((ext_vector_type(8)));
typedef float f32x4 __attribute__((ext_vector_type(4)));

__device__ __forceinline__ unsigned short bf16_rtn(float f) {
  unsigned u = __float_as_uint(f);
  return (unsigned short)((u + 0x7fffu + ((u >> 16) & 1u)) >> 16);
}
__device__ __forceinline__ float bf16_to_f(unsigned short v) {
  return __uint_as_float(((unsigned)v) << 16);
}
__device__ __forceinline__ void gload_lds16(const void* g, void* l) {
  __builtin_amdgcn_global_load_lds(
      (const __attribute__((address_space(1))) void*)g,
      (__attribute__((address_space(3))) void*)l, 16, 0, 0);
}

// Pack x[64][1024] into MFMA B-fragment lane order (hi/lo bf16 split),
// replicated 8x so each XCD's L2 can hold a private copy.
__global__ __launch_bounds__(256) void pack_x(const float* __restrict__ x,
                                              uint4* __restrict__ xpk8) {
  int tid = blockIdx.x * 256 + threadIdx.x;  // 0..8191
  int ks = tid >> 8;
  int g = (tid >> 6) & 3;
  int l = tid & 63;
  int b = g * 16 + (l & 15);
  int k0 = ks * 32 + (l >> 4) * 8;
  unsigned hi[8], lo[8];
#pragma unroll
  for (int j = 0; j < 8; ++j) {
    float f = x[b * DIN + k0 + j];
    unsigned u = __float_as_uint(f);
    hi[j] = u >> 16;  // truncate to bf16
    float fh = __uint_as_float(u & 0xffff0000u);
    lo[j] = bf16_rtn(f - fh);
  }
  uint4 vh, vl;
  vh.x = hi[0] | (hi[1] << 16); vh.y = hi[2] | (hi[3] << 16);
  vh.z = hi[4] | (hi[5] << 16); vh.w = hi[6] | (hi[7] << 16);
  vl.x = lo[0] | (lo[1] << 16); vl.y = lo[2] | (lo[3] << 16);
  vl.z = lo[4] | (lo[5] << 16); vl.w = lo[6] | (lo[7] << 16);
  int idx = (ks * 4 + g) * 128 + l;
#pragma unroll
  for (int c = 0; c < 8; ++c) {
    xpk8[(size_t)c * XPK_N + idx] = vh;
    xpk8[(size_t)c * XPK_N + idx + 64] = vl;
  }
}

// h[n][b] = relu(sum_d W0[n][d]*x[b][d] + b0[n]) via split-bf16 MFMA.
// 256-thr block = 4 waves, 64 rows/block. BOTH W and x staged HBM/L2->LDS
// via fire-and-forget global_load_lds (double-buffered, 1 barrier/kstep):
// zero dependent VMEM in the kstep body. x read from the XCD-local copy.
__global__ __launch_bounds__(256) void layer0_mfma(
    const float* __restrict__ W0, const float* __restrict__ b0,
    const uint4* __restrict__ xpk8, unsigned short* __restrict__ h)
{
  __shared__ float wlds[2][64 * 32];  // 8 KB per buf, XOR-swizzled rows
  __shared__ uint4 xlds[2][512];      // 8 KB per buf, linear
  const int t = threadIdx.x;
  const int lane = t & 63;
  const int w = t >> 6;       // wave id: rows w*16..w*16+15
  const int rq = lane >> 4;
  const int rr = lane & 15;
  const int n0 = blockIdx.x * 64;
  const uint4* xsrc = xpk8 + (size_t)(blockIdx.x & 7) * XPK_N;

  // W staging slots (linear LDS dest, inverse-swizzled global source)
  int s_row[2], s_srcg[2];
#pragma unroll
  for (int p = 0; p < 2; ++p) {
    int flat = p * 256 + t;
    s_row[p] = flat >> 3;
    s_srcg[p] = (flat & 7) ^ (s_row[p] & 7);
  }
  int rowg0 = n0 + s_row[0]; if (rowg0 > NV - 1) rowg0 = NV - 1;
  int rowg1 = n0 + s_row[1]; if (rowg1 > NV - 1) rowg1 = NV - 1;
  const float* sp0 = W0 + (size_t)rowg0 * DIN + s_srcg[0] * 4;
  const float* sp1 = W0 + (size_t)rowg1 * DIN + s_srcg[1] * 4;

  // per-lane swizzled W ds_read offsets (floats)
  const int myrow = w * 16 + rr;
  const int sw = (myrow & 7) << 4;
  const int off0 = (myrow * 128 + ((rq * 32) ^ sw)) >> 2;
  const int off1 = (myrow * 128 + ((rq * 32 + 16) ^ sw)) >> 2;

  f32x4 acc[4];
#pragma unroll
  for (int g = 0; g < 4; ++g) acc[g] = (f32x4){0.f, 0.f, 0.f, 0.f};

  // prologue: stage kstep 0 into buf 0
  gload_lds16(sp0, &wlds[0][(0 * 256 + t) * 4]);
  gload_lds16(sp1, &wlds[0][(1 * 256 + t) * 4]);
  gload_lds16(xsrc + (0 * 256 + t), &xlds[0][0 * 256 + t]);
  gload_lds16(xsrc + (1 * 256 + t), &xlds[0][1 * 256 + t]);
  __syncthreads();

  for (int ks = 0; ks < KSTEPS; ++ks) {
    const int cur = ks & 1;
    if (ks + 1 < KSTEPS) {
      const int ko = (ks + 1) * 32;
      gload_lds16(sp0 + ko, &wlds[cur ^ 1][(0 * 256 + t) * 4]);
      gload_lds16(sp1 + ko, &wlds[cur ^ 1][(1 * 256 + t) * 4]);
      const uint4* xs = xsrc + (ks + 1) * 512;
      gload_lds16(xs + (0 * 256 + t), &xlds[cur ^ 1][0 * 256 + t]);
      gload_lds16(xs + (1 * 256 + t), &xlds[cur ^ 1][1 * 256 + t]);
    }
    // x fragments from LDS (8x ds_read_b128, lane-linear = conflict-free)
    uint4 xc[4][2];
#pragma unroll
    for (int g = 0; g < 4; ++g) {
      xc[g][0] = xlds[cur][g * 128 + lane];
      xc[g][1] = xlds[cur][g * 128 + 64 + lane];
    }
    // W fragment from LDS (2x ds_read_b128, <=2-way via XOR swizzle)
    const float* wb = &wlds[cur][0];
    float4 wv0 = *(const float4*)(wb + off0);
    float4 wv1 = *(const float4*)(wb + off1);
    bf16x8 whi, wlo;
    {
      float wf[8] = {wv0.x, wv0.y, wv0.z, wv0.w, wv1.x, wv1.y, wv1.z, wv1.w};
#pragma unroll
      for (int e = 0; e < 8; ++e) {
        unsigned u = __float_as_uint(wf[e]);
        whi[e] = (short)(u >> 16);
        float l = wf[e] - __uint_as_float(u & 0xffff0000u);
        wlo[e] = (short)bf16_rtn(l);
      }
    }
#pragma unroll
    for (int g = 0; g < 4; ++g) {
      bf16x8 xh = __builtin_bit_cast(bf16x8, xc[g][0]);
      bf16x8 xl = __builtin_bit_cast(bf16x8, xc[g][1]);
      acc[g] = __builtin_amdgcn_mfma_f32_16x16x32_bf16(whi, xh, acc[g], 0, 0, 0);
      acc[g] = __builtin_amdgcn_mfma_f32_16x16x32_bf16(wlo, xh, acc[g], 0, 0, 0);
      acc[g] = __builtin_amdgcn_mfma_f32_16x16x32_bf16(whi, xl, acc[g], 0, 0, 0);
    }
    __syncthreads();  // vmcnt-drain: stage(ks+1) landed; buf reuse protected
  }

  // C layout: col = rr (b sub), row = rq*4 + r (n sub); rows of wave w
#pragma unroll
  for (int r = 0; r < 4; ++r) {
    int n = n0 + w * 16 + rq * 4 + r;
    if (n < NV) {
      float bias = b0[n];
#pragma unroll
      for (int g = 0; g < 4; ++g) {
        float v = fmaxf(acc[g][r] + bias, 0.f);
        h[(size_t)n * BDIM + g * 16 + rr] = bf16_rtn(v);
      }
    }
  }
}

// h_new[n][b] = relu(sum_k wv[n][k] * h[src[n][k]][b]); one wave per n.
__global__ __launch_bounds__(256) void sparse_layer(
    const unsigned short* __restrict__ hin, const float* __restrict__ wv,
    const int* __restrict__ src, unsigned short* __restrict__ hout)
{
  const int lane = threadIdx.x & 63;
  int n = blockIdx.x * 4 + (threadIdx.x >> 6);
  n = __builtin_amdgcn_readfirstlane(n);
  const float* wrow = wv + (size_t)n * KFAN;
  const int* srow = src + (size_t)n * KFAN;
  float acc = 0.f;
#pragma unroll
  for (int k = 0; k < KFAN; ++k) {
    int s = srow[k];      // uniform scalar load
    float w = wrow[k];    // uniform scalar load
    acc = fmaf(w, bf16_to_f(hin[(size_t)s * BDIM + lane]), acc);
  }
  hout[(size_t)n * BDIM + lane] = bf16_rtn(fmaxf(acc, 0.f));
}

// hT[b][n] = h[n][b]; coalesced reads, 16B/lane stores; zero-fills n-pad.
__global__ __launch_bounds__(256) void transpose_h(
    const unsigned short* __restrict__ h, unsigned short* __restrict__ hT)
{
  const int lane = threadIdx.x & 63;              // b
  const int wv = threadIdx.x >> 6;                // wave in block
  const int n0 = (blockIdx.x * 4 + wv) * 8;       // 8 n per wave
  unsigned short v[8];
#pragma unroll
  for (int i = 0; i < 8; ++i) {
    int n = n0 + i;
    v[i] = (n < NV) ? h[(size_t)n * BDIM + lane] : (unsigned short)0;
  }
  uint4 o;
  o.x = v[0] | ((unsigned)v[1] << 16);
  o.y = v[2] | ((unsigned)v[3] << 16);
  o.z = v[4] | ((unsigned)v[5] << 16);
  o.w = v[6] | ((unsigned)v[7] << 16);
  *(uint4*)(hT + (size_t)lane * NVP + n0) = o;
}

// part[dtile][chunk][d_local][b] over 128-n chunks, split-bf16 MFMA.
__global__ __launch_bounds__(64) void out_partial_mfma(
    const unsigned short* __restrict__ hT, const float* __restrict__ Wout,
    float* __restrict__ part)
{
  const int lane = threadIdx.x;
  const int rq = lane >> 4;
  const int rr = lane & 15;
  const int dtile = blockIdx.x;   // 0..3
  const int chunk = blockIdx.y;   // 0..391

  f32x4 acc[4][4];
#pragma unroll
  for (int f = 0; f < 4; ++f)
#pragma unroll
    for (int g = 0; g < 4; ++g) acc[f][g] = (f32x4){0.f, 0.f, 0.f, 0.f};

#pragma unroll
  for (int ks = 0; ks < OPC_CHUNK / 32; ++ks) {
    const int n0 = chunk * OPC_CHUNK + ks * 32 + rq * 8;
    bf16x8 hb[4];
#pragma unroll
    for (int g = 0; g < 4; ++g)
      hb[g] = *(const bf16x8*)(hT + (size_t)(g * 16 + rr) * NVP + n0);
    int nb = n0 > (NV - 8) ? (NV - 8) : n0;  // pad region: hb==0 -> contributes 0
#pragma unroll
    for (int f = 0; f < 4; ++f) {
      const float* wp = Wout + (size_t)(dtile * 64 + f * 16 + rr) * NV + nb;
      float4 a0 = *(const float4*)(wp);
      float4 a1 = *(const float4*)(wp + 4);
      float wf[8] = {a0.x, a0.y, a0.z, a0.w, a1.x, a1.y, a1.z, a1.w};
      bf16x8 whi, wlo;
#pragma unroll
      for (int e = 0; e < 8; ++e) {
        unsigned u = __float_as_uint(wf[e]);
        whi[e] = (short)(u >> 16);
        float l = wf[e] - __uint_as_float(u & 0xffff0000u);
        wlo[e] = (short)bf16_rtn(l);
      }
#pragma unroll
      for (int g = 0; g < 4; ++g) {
        acc[f][g] = __builtin_amdgcn_mfma_f32_16x16x32_bf16(whi, hb[g], acc[f][g], 0, 0, 0);
        acc[f][g] = __builtin_amdgcn_mfma_f32_16x16x32_bf16(wlo, hb[g], acc[f][g], 0, 0, 0);
      }
    }
  }
  float* pbase = part + ((size_t)dtile * OPC_NCH + chunk) * 4096;
#pragma unroll
  for (int f = 0; f < 4; ++f)
#pragma unroll
    for (int g = 0; g < 4; ++g)
#pragma unroll
      for (int r = 0; r < 4; ++r)
        pbase[(f * 16 + rq * 4 + r) * 64 + g * 16 + rr] = acc[f][g][r];
}

__global__ __launch_bounds__(256) void out_reduce(
    const float* __restrict__ part, const float* __restrict__ bout,
    float* __restrict__ out)
{
  int tid = blockIdx.x * 256 + threadIdx.x;  // 16384 threads
  int b = tid & 63;
  int d = tid >> 6;
  int dtile = d >> 6;
  int dd = d & 63;
  float s = bout[d];
  for (int c = 0; c < OPC_NCH; ++c)
    s += part[((size_t)dtile * OPC_NCH + c) * 4096 + dd * 64 + b];
  out[(size_t)b * DOUT + d] = s;
}

extern "C" void kernel_launch(void* const* d_in, const int* in_sizes, int n_in,
                              void* d_out, int out_size, void* d_ws, size_t ws_size,
                              hipStream_t stream)
{
  const float* x    = (const float*)d_in[0];
  const float* W0   = (const float*)d_in[1];
  const float* b0   = (const float*)d_in[2];
  const float* Wv   = (const float*)d_in[3];
  const float* Wout = (const float*)d_in[4];
  const float* bout = (const float*)d_in[5];
  const int*   src  = (const int*)d_in[6];
  float* out = (float*)d_out;

  char* ws = (char*)d_ws;
  const size_t hbf = (size_t)NV * BDIM * 2;       // 6.4 MB
  const size_t hTb = (size_t)NVP * BDIM * 2;      // 6.42 MB
  const size_t xpkb = (size_t)8 * XPK_N * 16;     // 2 MB
  unsigned short* hb0 = (unsigned short*)ws;
  unsigned short* hb1 = (unsigned short*)(ws + hbf);
  unsigned short* hT  = (unsigned short*)(ws + 2 * hbf);
  uint4* xpk8 = (uint4*)(ws + 2 * hbf + hTb);
  float* part = (float*)(ws + 2 * hbf + hTb + xpkb);  // 25.7 MB

  pack_x<<<32, 256, 0, stream>>>(x, xpk8);
  layer0_mfma<<<(NV + 63) / 64, 256, 0, stream>>>(W0, b0, xpk8, hb0);

  const size_t lstride = (size_t)NV * KFAN;
  sparse_layer<<<NV / 4, 256, 0, stream>>>(hb0, Wv, src, hb1);
  sparse_layer<<<NV / 4, 256, 0, stream>>>(hb1, Wv + lstride, src + lstride, hb0);
  sparse_layer<<<NV / 4, 256, 0, stream>>>(hb0, Wv + 2 * lstride, src + 2 * lstride, hb1);

  transpose_h<<<NVP / 32, 256, 0, stream>>>(hb1, hT);
  out_partial_mfma<<<dim3(4, OPC_NCH), 64, 0, stream>>>(hT, Wout, part);
  out_reduce<<<(BDIM * DOUT) / 256, 256, 0, stream>>>(part, bout, out);
}